// Round 1
// baseline (1361.747 us; speedup 1.0000x reference)
//
#include <hip/hip_runtime.h>

// Sizes
#define BB 64
#define LL 25
#define DD 128
#define BL 1600           // B*L
#define POI_N 10000
#define CAT_N 400
#define NBLK 150          // persistent-kernel grid: <= 256 CUs at 1 block/CU -> always co-resident

// ---------------------------------------------------------------------------
// Grid-wide barrier: one monotonic counter per barrier instance (no reuse, no
// sense reversal). Counters live in workspace, zeroed by hipMemsetAsync before
// launch. Release add + acquire spin at agent scope handles cross-XCD
// visibility (L2 writeback on release, L1/L2 invalidate on acquire).
// ---------------------------------------------------------------------------
__device__ __forceinline__ void gridbar(unsigned* __restrict__ bar, int id)
{
    __syncthreads();                               // drains this block's vmem (compiler emits vmcnt(0))
    if (threadIdx.x == 0) {
        __threadfence();                           // belt & braces: device-scope release
        __hip_atomic_fetch_add(&bar[id], 1u, __ATOMIC_RELEASE, __HIP_MEMORY_SCOPE_AGENT);
        while (__hip_atomic_load(&bar[id], __ATOMIC_ACQUIRE, __HIP_MEMORY_SCOPE_AGENT) < NBLK)
            __builtin_amdgcn_s_sleep(1);
        // note: every block (incl. the last arriver) executes >=1 acquire load
    }
    __syncthreads();
}

// ---------------------------------------------------------------------------
// One persistent kernel for the whole ac-chain:
//   phase E : embed gather (grid-stride) + distance min/max (grid-stride rows)
//   8 x     : proj (150 blocks) | corr (64) | top3+softmax+agg (50)
//   tail    : precat (64)
// 25 grid barriers. All former kernel bodies verbatim (corr vectorized).
// ---------------------------------------------------------------------------
__global__ __launch_bounds__(256) void persist_kernel(
    const int* __restrict__ user, const int* __restrict__ poi, const int* __restrict__ cat,
    const int* __restrict__ tod, const int* __restrict__ dow,
    const float* __restrict__ ue, const float* __restrict__ pe, const float* __restrict__ ce,
    const float* __restrict__ te, const float* __restrict__ de,
    const float* __restrict__ uec, const float* __restrict__ tec, const float* __restrict__ dec,
    const float* __restrict__ W, const float* __restrict__ Bv,
    const float* __restrict__ vw, const float* __restrict__ vbp,
    const float* __restrict__ Dm,
    float* __restrict__ O0, float* __restrict__ C0, float* __restrict__ O1, float* __restrict__ C1,
    float* __restrict__ Qb, float* __restrict__ Kb, float* __restrict__ Vb,
    float* __restrict__ MV,
    unsigned* __restrict__ bar, unsigned* __restrict__ mm,
    float* __restrict__ out_cat)
{
    // ---- shared memory: big region reused per phase + small persistent tail
    __shared__ __align__(16) char smem_raw[51712];     // proj/agg: sS[32][132] + sWc[128][68]
    float (*sS)[132] = reinterpret_cast<float(*)[132]>(smem_raw);
    float (*sWc)[68] = reinterpret_cast<float(*)[68]>(smem_raw + 16896);
    float* csq       = reinterpret_cast<float*>(smem_raw);            // corr: q rows [3200]
    float* csk       = reinterpret_cast<float*>(smem_raw + 12800);    // corr: k rows [3200]
    float (*crb)[4]  = reinterpret_cast<float(*)[4]>(smem_raw + 25600); // corr: rbuf[25][4]

    __shared__ float sbm[LL];          // batch-mean of mv
    __shared__ int   sidx[3];          // top-3 shifts
    __shared__ float stc[BB][3];       // per-b softmax weights
    __shared__ float redA[4], redB[4]; // minmax wave partials
    __shared__ float yv[DD];           // precat
    __shared__ float svw[LL];          // precat

    int bx = blockIdx.x, t = threadIdx.x;

    // ================= phase E: embed (+ distance min/max) =================
    for (int i = bx * 256 + t; i < 51200; i += NBLK * 256) {   // 204800 floats as float4
        int bl = i >> 5, c = (i & 31) << 2;
        int u = user[bl], p = poi[bl], cc = cat[bl], td = tod[bl], dw = dow[bl];
        float4 a0 = *(const float4*)(ue + u * DD + c);
        float4 a1 = *(const float4*)(pe + p * DD + c);
        float4 a2 = *(const float4*)(te + td * DD + c);
        float4 a3 = *(const float4*)(de + dw * DD + c);
        float4 x;
        x.x = a0.x + a1.x + a2.x + a3.x; x.y = a0.y + a1.y + a2.y + a3.y;
        x.z = a0.z + a1.z + a2.z + a3.z; x.w = a0.w + a1.w + a2.w + a3.w;
        *(float4*)(O0 + bl * DD + c) = x;
        float4 b0 = *(const float4*)(uec + u * DD + c);
        float4 b1 = *(const float4*)(ce + cc * DD + c);
        float4 b2 = *(const float4*)(tec + td * DD + c);
        float4 b3 = *(const float4*)(dec + dw * DD + c);
        float4 xc;
        xc.x = b0.x + b1.x + b2.x + b3.x; xc.y = b0.y + b1.y + b2.y + b3.y;
        xc.z = b0.z + b1.z + b2.z + b3.z; xc.w = b0.w + b1.w + b2.w + b3.w;
        *(float4*)(C0 + bl * DD + c) = xc;
    }
    {   // min/max over the 1600 gathered distance rows (grid-stride rows).
        // mm memset to 0: max via bits (floats >= 0); min via max of ~bits.
        float mx = -1e30f, mn = 1e30f;
        for (int row = bx; row < BL; row += NBLK) {
            const float4* r4 = (const float4*)(Dm + (size_t)poi[row] * POI_N);
            for (int i = t; i < POI_N / 4; i += 256) {
                float4 v4 = r4[i];
                mx = fmaxf(mx, fmaxf(fmaxf(v4.x, v4.y), fmaxf(v4.z, v4.w)));
                mn = fminf(mn, fminf(fminf(v4.x, v4.y), fminf(v4.z, v4.w)));
            }
        }
        for (int off = 32; off > 0; off >>= 1) {
            mx = fmaxf(mx, __shfl_down(mx, off));
            mn = fminf(mn, __shfl_down(mn, off));
        }
        if ((t & 63) == 0) { redA[t >> 6] = mx; redB[t >> 6] = mn; }
        __syncthreads();
        if (t == 0) {
            mx = fmaxf(fmaxf(redA[0], redA[1]), fmaxf(redA[2], redA[3]));
            mn = fminf(fminf(redB[0], redB[1]), fminf(redB[2], redB[3]));
            atomicMax(&mm[0], __float_as_uint(mx));
            atomicMax(&mm[1], ~__float_as_uint(mn));   // min(x) = ~max(~bits)
        }
    }
    gridbar(bar, 0);

    // ================= 8 autocorrelation-attention calls ===================
    float* bufs[4] = {O0, C0, O1, C1};
    const int qsel[8] = {0, 1, 2, 3, 0, 1, 2, 3};
    const int ksel[8] = {0, 1, 3, 0, 0, 1, 3, 0};
    const int dsel[8] = {2, 3, 0, 1, 2, 3, 0, 1};
    int bid = 1;

#pragma unroll 1
    for (int ci = 0; ci < 8; ++ci) {
        const float* qx  = bufs[qsel[ci]];
        const float* kx  = bufs[ksel[ci]];   // kx == vx in all calls
        float*       dst = bufs[dsel[ci]];
        const float* Wb  = W  + (size_t)ci * 4 * DD * DD;
        const float* Bb  = Bv + (size_t)ci * 4 * DD;

        // ---- proj: dst3 = src @ Wr^T + br for r in {q,k,v}; all 150 blocks
        {
            int r = bx / 50, tile = bx % 50;
            const float* src  = (r == 0) ? qx : kx;
            const float* Wm   = Wb + r * DD * DD;
            const float* bias = Bb + r * DD;
            float* pdst       = (r == 0) ? Qb : (r == 1 ? Kb : Vb);
            int mbase = tile * 32;

            for (int i = t; i < 32 * 32; i += 256) {
                int m = i >> 5, c = (i & 31) << 2;
                *(float4*)&sS[m][c] = *(const float4*)(src + (mbase + m) * DD + c);
            }
            __syncthreads();
            int nh = t & 31, mg = t >> 5;
            float acc[4][4] = {};
            for (int kb = 0; kb < 128; kb += 64) {
                for (int i = t; i < 128 * 16; i += 256) {
                    int n = i >> 4, c = (i & 15) << 2;
                    *(float4*)&sWc[n][c] = *(const float4*)(Wm + n * DD + kb + c);
                }
                __syncthreads();
#pragma unroll 4
                for (int kk = 0; kk < 64; kk += 4) {
                    float4 a[4], w[4];
#pragma unroll
                    for (int i2 = 0; i2 < 4; i2++) a[i2] = *(const float4*)&sS[mg * 4 + i2][kb + kk];
#pragma unroll
                    for (int j = 0; j < 4; j++) w[j] = *(const float4*)&sWc[nh + 32 * j][kk];
#pragma unroll
                    for (int i2 = 0; i2 < 4; i2++)
#pragma unroll
                        for (int j = 0; j < 4; j++)
                            acc[i2][j] += a[i2].x * w[j].x + a[i2].y * w[j].y +
                                          a[i2].z * w[j].z + a[i2].w * w[j].w;
                }
                __syncthreads();
            }
#pragma unroll
            for (int i2 = 0; i2 < 4; i2++) {
                int m = mbase + mg * 4 + i2;
#pragma unroll
                for (int j = 0; j < 4; j++) {
                    int n = nh + 32 * j;
                    pdst[m * DD + n] = acc[i2][j] + bias[n];
                }
            }
        }
        gridbar(bar, bid++);

        // ---- corr: mv[b,tau] = (1/128) sum_s q[b,(s+tau)%25,:].k[b,s,:]; 64 blocks
        if (bx < BB) {
            int b = bx;
            for (int i = t; i < 800; i += 256) {
                int c = i << 2;
                *(float4*)&csq[c] = *(const float4*)(Qb + b * LL * DD + c);
                *(float4*)&csk[c] = *(const float4*)(Kb + b * LL * DD + c);
            }
            __syncthreads();
            int lid = t & 63, wid = t >> 6;
            for (int tau = 0; tau < LL; tau++) {
                float s = 0.f;
                for (int e = t; e < 800; e += 256) {        // float4 granularity
                    int srow = e >> 5, dc = (e & 31) << 2;
                    int qrow = srow + tau; if (qrow >= LL) qrow -= LL;
                    float4 a = *(const float4*)&csq[qrow * DD + dc];
                    float4 g = *(const float4*)&csk[srow * DD + dc];
                    s += a.x * g.x + a.y * g.y + a.z * g.z + a.w * g.w;
                }
                for (int off = 32; off > 0; off >>= 1) s += __shfl_down(s, off);
                if (lid == 0) crb[tau][wid] = s;
            }
            __syncthreads();
            if (t < LL)
                MV[b * LL + t] = (crb[t][0] + crb[t][1] + crb[t][2] + crb[t][3]) * (1.0f / 128.0f);
        }
        gridbar(bar, bid++);

        // ---- top3 (redundant per block) + softmax + agg + out-proj; 50 blocks
        if (bx < 50) {
            int mbase = bx * 32;
            if (t < LL) {
                float s = 0.f;
                for (int b2 = 0; b2 < BB; b2++) s += MV[b2 * LL + t];
                sbm[t] = s;
            }
            __syncthreads();
            if (t == 0) {
                float loc[LL];
                for (int i = 0; i < LL; i++) loc[i] = sbm[i];
                for (int j = 0; j < 3; j++) {
                    int bi = 0; float bvv = loc[0];
                    for (int i = 1; i < LL; i++) if (loc[i] > bvv) { bvv = loc[i]; bi = i; }
                    sidx[j] = bi; loc[bi] = -1e30f;
                }
            }
            __syncthreads();
            if (t < BB) {
                float w0 = MV[t * LL + sidx[0]];
                float w1 = MV[t * LL + sidx[1]];
                float w2 = MV[t * LL + sidx[2]];
                float m = fmaxf(w0, fmaxf(w1, w2));
                float e0 = expf(w0 - m), e1 = expf(w1 - m), e2 = expf(w2 - m);
                float inv = 1.0f / (e0 + e1 + e2);
                stc[t][0] = e0 * inv; stc[t][1] = e1 * inv; stc[t][2] = e2 * inv;
            }
            __syncthreads();
            int i0 = sidx[0], i1 = sidx[1], i2x = sidx[2];
            const float* Wm   = Wb + 3 * DD * DD;
            const float* bias = Bb + 3 * DD;

            for (int i = t; i < 32 * 32; i += 256) {
                int m = i >> 5, c = (i & 31) << 2;
                int row = mbase + m;
                int b = row / LL, l = row - b * LL;
                int l0 = l + i0;  if (l0 >= LL) l0 -= LL;
                int l1 = l + i1;  if (l1 >= LL) l1 -= LL;
                int l2 = l + i2x; if (l2 >= LL) l2 -= LL;
                float w0 = stc[b][0], w1 = stc[b][1], w2 = stc[b][2];
                float4 v0 = *(const float4*)(Vb + (b * LL + l0) * DD + c);
                float4 v1 = *(const float4*)(Vb + (b * LL + l1) * DD + c);
                float4 v2 = *(const float4*)(Vb + (b * LL + l2) * DD + c);
                float4 a;
                a.x = w0 * v0.x + w1 * v1.x + w2 * v2.x;
                a.y = w0 * v0.y + w1 * v1.y + w2 * v2.y;
                a.z = w0 * v0.z + w1 * v1.z + w2 * v2.z;
                a.w = w0 * v0.w + w1 * v1.w + w2 * v2.w;
                *(float4*)&sS[m][c] = a;
            }
            __syncthreads();
            int nh = t & 31, mg = t >> 5;
            float acc[4][4] = {};
            for (int kb = 0; kb < 128; kb += 64) {
                for (int i = t; i < 128 * 16; i += 256) {
                    int n = i >> 4, c = (i & 15) << 2;
                    *(float4*)&sWc[n][c] = *(const float4*)(Wm + n * DD + kb + c);
                }
                __syncthreads();
#pragma unroll 4
                for (int kk = 0; kk < 64; kk += 4) {
                    float4 a[4], w[4];
#pragma unroll
                    for (int ii = 0; ii < 4; ii++) a[ii] = *(const float4*)&sS[mg * 4 + ii][kb + kk];
#pragma unroll
                    for (int j = 0; j < 4; j++) w[j] = *(const float4*)&sWc[nh + 32 * j][kk];
#pragma unroll
                    for (int ii = 0; ii < 4; ii++)
#pragma unroll
                        for (int j = 0; j < 4; j++)
                            acc[ii][j] += a[ii].x * w[j].x + a[ii].y * w[j].y +
                                          a[ii].z * w[j].z + a[ii].w * w[j].w;
                }
                __syncthreads();
            }
#pragma unroll
            for (int ii = 0; ii < 4; ii++) {
                int m = mbase + mg * 4 + ii;
#pragma unroll
                for (int j = 0; j < 4; j++) {
                    int n = nh + 32 * j;
                    dst[m * DD + n] = acc[ii][j] + bias[n];
                }
            }
        }
        gridbar(bar, bid++);
    }

    // ================= precat tail (64 blocks) =============================
    if (bx < BB) {
        int b = bx;
        if (t < LL) svw[t] = vw[t];
        __syncthreads();
        if (t < DD) {
            float s = 0.f;
            for (int l = 0; l < LL; l++) s += svw[l] * C0[(b * LL + l) * DD + t];
            yv[t] = s;
        }
        __syncthreads();
        float vb = vbp[0];
        for (int c = t; c < CAT_N; c += 256) {
            float s = 0.f;
            for (int d = 0; d < DD; d += 4) {
                float4 ce4 = *(const float4*)(ce + c * DD + d);
                s += ce4.x * yv[d] + ce4.y * yv[d + 1] + ce4.z * yv[d + 2] + ce4.w * yv[d + 3];
            }
            out_cat[b * CAT_N + c] = s + vb;
        }
    }
}

// ---------------------------------------------------------------------------
// pre_poi[b,p] = vb + sum_l vw[l] * exp(-D[poi[b,l],p]/(gmax-gmin))
//                                 * (poi_emb[p] . out[b,l,:])
// Unchanged from verified kernel except gmin decode (~bits trick).
// ---------------------------------------------------------------------------
__global__ __launch_bounds__(256) void prepoi_kernel(
    const float* __restrict__ outp, const float* __restrict__ poi_emb,
    const int* __restrict__ poi_idx, const float* __restrict__ Dm,
    const unsigned* __restrict__ mm, const float* __restrict__ vw,
    const float* __restrict__ vbp, float* __restrict__ dstp)
{
    int b = blockIdx.y;
    int pbase = blockIdx.x << 7;
    __shared__ float sO[LL][132];
    __shared__ float sPc[128][68];
    __shared__ float sS[LL][132];
    __shared__ float svw[LL];
    __shared__ int srow[LL];
    __shared__ float red[128];
    int t = threadIdx.x;

    for (int i = t; i < 800; i += 256) {
        int l = i >> 5, c = (i & 31) << 2;
        *(float4*)&sO[l][c] = *(const float4*)(outp + (b * LL + l) * DD + c);
    }
    if (t < LL) { svw[t] = vw[t]; srow[t] = poi_idx[b * LL + t]; }
    __syncthreads();

    int nh = t & 31, mg = t >> 5;
    float acc[4][4] = {};
    for (int kb = 0; kb < 128; kb += 64) {
        for (int i = t; i < 128 * 16; i += 256) {
            int p = i >> 4, c = (i & 15) << 2;
            float4 val = {0.f, 0.f, 0.f, 0.f};
            if (pbase + p < POI_N) val = *(const float4*)(poi_emb + (pbase + p) * DD + kb + c);
            *(float4*)&sPc[p][c] = val;
        }
        __syncthreads();
#pragma unroll 4
        for (int kk = 0; kk < 64; kk += 4) {
            float4 a0 = *(const float4*)&sO[mg][kb + kk];
            float4 a1 = *(const float4*)&sO[mg + 8][kb + kk];
            float4 a2 = *(const float4*)&sO[mg + 16][kb + kk];
            float4 a3 = {0.f, 0.f, 0.f, 0.f};
            if (mg == 0) a3 = *(const float4*)&sO[24][kb + kk];
#pragma unroll
            for (int j = 0; j < 4; j++) {
                float4 p4 = *(const float4*)&sPc[nh + 32 * j][kk];
                acc[j][0] += p4.x * a0.x + p4.y * a0.y + p4.z * a0.z + p4.w * a0.w;
                acc[j][1] += p4.x * a1.x + p4.y * a1.y + p4.z * a1.z + p4.w * a1.w;
                acc[j][2] += p4.x * a2.x + p4.y * a2.y + p4.z * a2.z + p4.w * a2.w;
                acc[j][3] += p4.x * a3.x + p4.y * a3.y + p4.z * a3.z + p4.w * a3.w;
            }
        }
        __syncthreads();
    }
#pragma unroll
    for (int j = 0; j < 4; j++) {
        int pl = nh + 32 * j;
        sS[mg][pl]      = acc[j][0];
        sS[mg + 8][pl]  = acc[j][1];
        sS[mg + 16][pl] = acc[j][2];
        if (mg == 0) sS[24][pl] = acc[j][3];
    }
    __syncthreads();

    float gmax = __uint_as_float(mm[0]);
    float gmin = __uint_as_float(~mm[1]);
    float ninv = -1.0f / (gmax - gmin);
    int pp = t & 127, half = t >> 7;
    int p = pbase + pp;
    float s = 0.f;
    if (p < POI_N) {
        int l0 = half ? 13 : 0, l1 = half ? 25 : 13;
        for (int l = l0; l < l1; l++) {
            float dv = Dm[(size_t)srow[l] * POI_N + p];
            s += svw[l] * expf(dv * ninv) * sS[l][pp];
        }
    }
    if (half) red[pp] = s;
    __syncthreads();
    if (!half && p < POI_N)
        dstp[(size_t)b * POI_N + p] = s + red[pp] + vbp[0];
}

// ---------------------------------------------------------------------------
extern "C" void kernel_launch(void* const* d_in, const int* in_sizes, int n_in,
                              void* d_out, int out_size, void* d_ws, size_t ws_size,
                              hipStream_t stream)
{
    const int*   user = (const int*)d_in[0];
    const int*   poi  = (const int*)d_in[1];
    const int*   cat  = (const int*)d_in[2];
    const int*   tod  = (const int*)d_in[5];
    const int*   dow  = (const int*)d_in[6];
    const float* ue   = (const float*)d_in[8];
    const float* pe   = (const float*)d_in[9];
    const float* ce   = (const float*)d_in[10];
    const float* te   = (const float*)d_in[11];
    const float* de   = (const float*)d_in[12];
    const float* uec  = (const float*)d_in[13];
    const float* tec  = (const float*)d_in[14];
    const float* dec  = (const float*)d_in[15];
    const float* W    = (const float*)d_in[16];
    const float* Bv   = (const float*)d_in[17];
    const float* vw   = (const float*)d_in[18];
    const float* vb   = (const float*)d_in[19];
    const float* Dm   = (const float*)d_in[20];

    float* ws = (float*)d_ws;
    float* O0 = ws;
    float* C0 = ws + 204800;
    float* O1 = ws + 409600;
    float* C1 = ws + 614400;
    float* Q  = ws + 819200;
    float* Kb = ws + 1024000;
    float* V  = ws + 1228800;
    float* MV = ws + 1433600;                      // 1600 floats
    unsigned* BAR = (unsigned*)(ws + 1435200);     // 32 barrier counters
    unsigned* MM  = BAR + 32;                      // 2 minmax slots

    float* out_poi = (float*)d_out;
    float* out_cat = out_poi + BB * POI_N;

    // zero barrier counters + minmax slots (max-trick needs 0-init for both)
    hipMemsetAsync(BAR, 0, 34 * sizeof(unsigned), stream);

    persist_kernel<<<NBLK, 256, 0, stream>>>(
        user, poi, cat, tod, dow, ue, pe, ce, te, de, uec, tec, dec,
        W, Bv, vw, vb, Dm, O0, C0, O1, C1, Q, Kb, V, MV, BAR, MM, out_cat);

    prepoi_kernel<<<dim3(79, BB), 256, 0, stream>>>(O0, pe, poi, Dm, MM, vw, vb, out_poi);
}

// Round 2
// 1263.416 us; speedup vs baseline: 1.0778x; 1.0778x over previous
//
#include <hip/hip_runtime.h>

// Sizes
#define BB 64
#define LL 25
#define DD 128
#define BL 1600           // B*L
#define POI_N 10000
#define CAT_N 400
#define NBLK 150          // persistent-kernel grid: <= 256 CUs at 1 block/CU -> always co-resident

// ---------------------------------------------------------------------------
// Grid-wide barrier. Arrival: release fetch_add (emits L2 writeback, making
// this block's prior stores visible at the coherence point). Spin: RELAXED
// agent-scope load -- reads the coherence point but emits NO cache
// invalidate (an ACQUIRE load here emits buffer_inv PER POLL: 150 spinners
// x ~5 polls/us = continuous chip-wide L2 invalidation storm -- the round-1
// 725us pathology). One __threadfence() after the spin does the single
// acquire invalidate for the whole block.
// ---------------------------------------------------------------------------
__device__ __forceinline__ void gridbar(unsigned* __restrict__ bar, int id)
{
    __syncthreads();
    if (threadIdx.x == 0) {
        __hip_atomic_fetch_add(&bar[id], 1u, __ATOMIC_RELEASE, __HIP_MEMORY_SCOPE_AGENT);
        while (__hip_atomic_load(&bar[id], __ATOMIC_RELAXED, __HIP_MEMORY_SCOPE_AGENT) < NBLK)
            __builtin_amdgcn_s_sleep(1);
        __threadfence();   // single acquire: L1/L2 invalidate once per barrier
    }
    __syncthreads();
}

// ---------------------------------------------------------------------------
// Distance min/max over the 1600 gathered rows -- standalone again: its
// result is consumed ONLY by prepoi_kernel (never by the ac-chain), and as a
// 1600-block kernel it has 6400 waves of memory parallelism (vs 600 inside
// the persistent kernel). mm zero-initialized by memset; min via ~bits trick.
// ---------------------------------------------------------------------------
__global__ __launch_bounds__(256) void minmax_kernel(
    const int* __restrict__ poi, const float* __restrict__ Dm, unsigned* __restrict__ mm)
{
    int bl = blockIdx.x;
    const float4* r = (const float4*)(Dm + (size_t)poi[bl] * POI_N);
    float mx = -1e30f, mn = 1e30f;
    for (int i = threadIdx.x; i < POI_N / 4; i += 256) {
        float4 v4 = r[i];
        mx = fmaxf(mx, fmaxf(fmaxf(v4.x, v4.y), fmaxf(v4.z, v4.w)));
        mn = fminf(mn, fminf(fminf(v4.x, v4.y), fminf(v4.z, v4.w)));
    }
    for (int off = 32; off > 0; off >>= 1) {
        mx = fmaxf(mx, __shfl_down(mx, off));
        mn = fminf(mn, __shfl_down(mn, off));
    }
    __shared__ float smx[4], smn[4];
    int lid = threadIdx.x & 63, wid = threadIdx.x >> 6;
    if (lid == 0) { smx[wid] = mx; smn[wid] = mn; }
    __syncthreads();
    if (threadIdx.x == 0) {
        mx = fmaxf(fmaxf(smx[0], smx[1]), fmaxf(smx[2], smx[3]));
        mn = fminf(fminf(smn[0], smn[1]), fminf(smn[2], smn[3]));
        atomicMax(&mm[0], __float_as_uint(mx));
        atomicMax(&mm[1], ~__float_as_uint(mn));   // min(x) = ~max(~bits), x >= 0
    }
}

// ---------------------------------------------------------------------------
// One persistent kernel for the ac-chain:
//   phase E : embed gather (grid-stride)
//   8 x     : proj (150 blocks) | corr (64) | top3+softmax+agg (50)
//   tail    : precat (64)
// 25 grid barriers. Phase bodies verbatim from the verified kernels.
// ---------------------------------------------------------------------------
__global__ __launch_bounds__(256) void persist_kernel(
    const int* __restrict__ user, const int* __restrict__ poi, const int* __restrict__ cat,
    const int* __restrict__ tod, const int* __restrict__ dow,
    const float* __restrict__ ue, const float* __restrict__ pe, const float* __restrict__ ce,
    const float* __restrict__ te, const float* __restrict__ de,
    const float* __restrict__ uec, const float* __restrict__ tec, const float* __restrict__ dec,
    const float* __restrict__ W, const float* __restrict__ Bv,
    const float* __restrict__ vw, const float* __restrict__ vbp,
    float* __restrict__ O0, float* __restrict__ C0, float* __restrict__ O1, float* __restrict__ C1,
    float* __restrict__ Qb, float* __restrict__ Kb, float* __restrict__ Vb,
    float* __restrict__ MV,
    unsigned* __restrict__ bar,
    float* __restrict__ out_cat)
{
    // ---- shared memory: big region reused per phase + small persistent tail
    __shared__ __align__(16) char smem_raw[51712];     // proj/agg: sS[32][132] + sWc[128][68]
    float (*sS)[132] = reinterpret_cast<float(*)[132]>(smem_raw);
    float (*sWc)[68] = reinterpret_cast<float(*)[68]>(smem_raw + 16896);
    float* csq       = reinterpret_cast<float*>(smem_raw);              // corr: q rows [3200]
    float* csk       = reinterpret_cast<float*>(smem_raw + 12800);      // corr: k rows [3200]
    float (*crb)[4]  = reinterpret_cast<float(*)[4]>(smem_raw + 25600); // corr: rbuf[25][4]

    __shared__ float sbm[LL];          // batch-mean of mv
    __shared__ int   sidx[3];          // top-3 shifts
    __shared__ float stc[BB][3];       // per-b softmax weights
    __shared__ float yv[DD];           // precat
    __shared__ float svw[LL];          // precat

    int bx = blockIdx.x, t = threadIdx.x;

    // ================= phase E: embed gather ===============================
    for (int i = bx * 256 + t; i < 51200; i += NBLK * 256) {   // 204800 floats as float4
        int bl = i >> 5, c = (i & 31) << 2;
        int u = user[bl], p = poi[bl], cc = cat[bl], td = tod[bl], dw = dow[bl];
        float4 a0 = *(const float4*)(ue + u * DD + c);
        float4 a1 = *(const float4*)(pe + p * DD + c);
        float4 a2 = *(const float4*)(te + td * DD + c);
        float4 a3 = *(const float4*)(de + dw * DD + c);
        float4 x;
        x.x = a0.x + a1.x + a2.x + a3.x; x.y = a0.y + a1.y + a2.y + a3.y;
        x.z = a0.z + a1.z + a2.z + a3.z; x.w = a0.w + a1.w + a2.w + a3.w;
        *(float4*)(O0 + bl * DD + c) = x;
        float4 b0 = *(const float4*)(uec + u * DD + c);
        float4 b1 = *(const float4*)(ce + cc * DD + c);
        float4 b2 = *(const float4*)(tec + td * DD + c);
        float4 b3 = *(const float4*)(dec + dw * DD + c);
        float4 xc;
        xc.x = b0.x + b1.x + b2.x + b3.x; xc.y = b0.y + b1.y + b2.y + b3.y;
        xc.z = b0.z + b1.z + b2.z + b3.z; xc.w = b0.w + b1.w + b2.w + b3.w;
        *(float4*)(C0 + bl * DD + c) = xc;
    }
    gridbar(bar, 0);

    // ================= 8 autocorrelation-attention calls ===================
    float* bufs[4] = {O0, C0, O1, C1};
    const int qsel[8] = {0, 1, 2, 3, 0, 1, 2, 3};
    const int ksel[8] = {0, 1, 3, 0, 0, 1, 3, 0};
    const int dsel[8] = {2, 3, 0, 1, 2, 3, 0, 1};
    int bid = 1;

#pragma unroll 1
    for (int ci = 0; ci < 8; ++ci) {
        const float* qx  = bufs[qsel[ci]];
        const float* kx  = bufs[ksel[ci]];   // kx == vx in all calls
        float*       dst = bufs[dsel[ci]];
        const float* Wb  = W  + (size_t)ci * 4 * DD * DD;
        const float* Bb  = Bv + (size_t)ci * 4 * DD;

        // ---- proj: dst3 = src @ Wr^T + br for r in {q,k,v}; all 150 blocks
        {
            int r = bx / 50, tile = bx % 50;
            const float* src  = (r == 0) ? qx : kx;
            const float* Wm   = Wb + r * DD * DD;
            const float* bias = Bb + r * DD;
            float* pdst       = (r == 0) ? Qb : (r == 1 ? Kb : Vb);
            int mbase = tile * 32;

            for (int i = t; i < 32 * 32; i += 256) {
                int m = i >> 5, c = (i & 31) << 2;
                *(float4*)&sS[m][c] = *(const float4*)(src + (mbase + m) * DD + c);
            }
            __syncthreads();
            int nh = t & 31, mg = t >> 5;
            float acc[4][4] = {};
            for (int kb = 0; kb < 128; kb += 64) {
                for (int i = t; i < 128 * 16; i += 256) {
                    int n = i >> 4, c = (i & 15) << 2;
                    *(float4*)&sWc[n][c] = *(const float4*)(Wm + n * DD + kb + c);
                }
                __syncthreads();
#pragma unroll 4
                for (int kk = 0; kk < 64; kk += 4) {
                    float4 a[4], w[4];
#pragma unroll
                    for (int i2 = 0; i2 < 4; i2++) a[i2] = *(const float4*)&sS[mg * 4 + i2][kb + kk];
#pragma unroll
                    for (int j = 0; j < 4; j++) w[j] = *(const float4*)&sWc[nh + 32 * j][kk];
#pragma unroll
                    for (int i2 = 0; i2 < 4; i2++)
#pragma unroll
                        for (int j = 0; j < 4; j++)
                            acc[i2][j] += a[i2].x * w[j].x + a[i2].y * w[j].y +
                                          a[i2].z * w[j].z + a[i2].w * w[j].w;
                }
                __syncthreads();
            }
#pragma unroll
            for (int i2 = 0; i2 < 4; i2++) {
                int m = mbase + mg * 4 + i2;
#pragma unroll
                for (int j = 0; j < 4; j++) {
                    int n = nh + 32 * j;
                    pdst[m * DD + n] = acc[i2][j] + bias[n];
                }
            }
        }
        gridbar(bar, bid++);

        // ---- corr: mv[b,tau] = (1/128) sum_s q[b,(s+tau)%25,:].k[b,s,:]; 64 blocks
        if (bx < BB) {
            int b = bx;
            for (int i = t; i < 800; i += 256) {
                int c = i << 2;
                *(float4*)&csq[c] = *(const float4*)(Qb + b * LL * DD + c);
                *(float4*)&csk[c] = *(const float4*)(Kb + b * LL * DD + c);
            }
            __syncthreads();
            int lid = t & 63, wid = t >> 6;
            for (int tau = 0; tau < LL; tau++) {
                float s = 0.f;
                for (int e = t; e < 800; e += 256) {        // float4 granularity
                    int srow = e >> 5, dc = (e & 31) << 2;
                    int qrow = srow + tau; if (qrow >= LL) qrow -= LL;
                    float4 a = *(const float4*)&csq[qrow * DD + dc];
                    float4 g = *(const float4*)&csk[srow * DD + dc];
                    s += a.x * g.x + a.y * g.y + a.z * g.z + a.w * g.w;
                }
                for (int off = 32; off > 0; off >>= 1) s += __shfl_down(s, off);
                if (lid == 0) crb[tau][wid] = s;
            }
            __syncthreads();
            if (t < LL)
                MV[b * LL + t] = (crb[t][0] + crb[t][1] + crb[t][2] + crb[t][3]) * (1.0f / 128.0f);
        }
        gridbar(bar, bid++);

        // ---- top3 (redundant per block) + softmax + agg + out-proj; 50 blocks
        if (bx < 50) {
            int mbase = bx * 32;
            if (t < LL) {
                float s = 0.f;
                for (int b2 = 0; b2 < BB; b2++) s += MV[b2 * LL + t];
                sbm[t] = s;
            }
            __syncthreads();
            if (t == 0) {
                float loc[LL];
                for (int i = 0; i < LL; i++) loc[i] = sbm[i];
                for (int j = 0; j < 3; j++) {
                    int bi = 0; float bvv = loc[0];
                    for (int i = 1; i < LL; i++) if (loc[i] > bvv) { bvv = loc[i]; bi = i; }
                    sidx[j] = bi; loc[bi] = -1e30f;
                }
            }
            __syncthreads();
            if (t < BB) {
                float w0 = MV[t * LL + sidx[0]];
                float w1 = MV[t * LL + sidx[1]];
                float w2 = MV[t * LL + sidx[2]];
                float m = fmaxf(w0, fmaxf(w1, w2));
                float e0 = expf(w0 - m), e1 = expf(w1 - m), e2 = expf(w2 - m);
                float inv = 1.0f / (e0 + e1 + e2);
                stc[t][0] = e0 * inv; stc[t][1] = e1 * inv; stc[t][2] = e2 * inv;
            }
            __syncthreads();
            int i0 = sidx[0], i1 = sidx[1], i2x = sidx[2];
            const float* Wm   = Wb + 3 * DD * DD;
            const float* bias = Bb + 3 * DD;

            for (int i = t; i < 32 * 32; i += 256) {
                int m = i >> 5, c = (i & 31) << 2;
                int row = mbase + m;
                int b = row / LL, l = row - b * LL;
                int l0 = l + i0;  if (l0 >= LL) l0 -= LL;
                int l1 = l + i1;  if (l1 >= LL) l1 -= LL;
                int l2 = l + i2x; if (l2 >= LL) l2 -= LL;
                float w0 = stc[b][0], w1 = stc[b][1], w2 = stc[b][2];
                float4 v0 = *(const float4*)(Vb + (b * LL + l0) * DD + c);
                float4 v1 = *(const float4*)(Vb + (b * LL + l1) * DD + c);
                float4 v2 = *(const float4*)(Vb + (b * LL + l2) * DD + c);
                float4 a;
                a.x = w0 * v0.x + w1 * v1.x + w2 * v2.x;
                a.y = w0 * v0.y + w1 * v1.y + w2 * v2.y;
                a.z = w0 * v0.z + w1 * v1.z + w2 * v2.z;
                a.w = w0 * v0.w + w1 * v1.w + w2 * v2.w;
                *(float4*)&sS[m][c] = a;
            }
            __syncthreads();
            int nh = t & 31, mg = t >> 5;
            float acc[4][4] = {};
            for (int kb = 0; kb < 128; kb += 64) {
                for (int i = t; i < 128 * 16; i += 256) {
                    int n = i >> 4, c = (i & 15) << 2;
                    *(float4*)&sWc[n][c] = *(const float4*)(Wm + n * DD + kb + c);
                }
                __syncthreads();
#pragma unroll 4
                for (int kk = 0; kk < 64; kk += 4) {
                    float4 a[4], w[4];
#pragma unroll
                    for (int ii = 0; ii < 4; ii++) a[ii] = *(const float4*)&sS[mg * 4 + ii][kb + kk];
#pragma unroll
                    for (int j = 0; j < 4; j++) w[j] = *(const float4*)&sWc[nh + 32 * j][kk];
#pragma unroll
                    for (int ii = 0; ii < 4; ii++)
#pragma unroll
                        for (int j = 0; j < 4; j++)
                            acc[ii][j] += a[ii].x * w[j].x + a[ii].y * w[j].y +
                                          a[ii].z * w[j].z + a[ii].w * w[j].w;
                }
                __syncthreads();
            }
#pragma unroll
            for (int ii = 0; ii < 4; ii++) {
                int m = mbase + mg * 4 + ii;
#pragma unroll
                for (int j = 0; j < 4; j++) {
                    int n = nh + 32 * j;
                    dst[m * DD + n] = acc[ii][j] + bias[n];
                }
            }
        }
        gridbar(bar, bid++);
    }

    // ================= precat tail (64 blocks) =============================
    if (bx < BB) {
        int b = bx;
        if (t < LL) svw[t] = vw[t];
        __syncthreads();
        if (t < DD) {
            float s = 0.f;
            for (int l = 0; l < LL; l++) s += svw[l] * C0[(b * LL + l) * DD + t];
            yv[t] = s;
        }
        __syncthreads();
        float vb = vbp[0];
        for (int c = t; c < CAT_N; c += 256) {
            float s = 0.f;
            for (int d = 0; d < DD; d += 4) {
                float4 ce4 = *(const float4*)(ce + c * DD + d);
                s += ce4.x * yv[d] + ce4.y * yv[d + 1] + ce4.z * yv[d + 2] + ce4.w * yv[d + 3];
            }
            out_cat[b * CAT_N + c] = s + vb;
        }
    }
}

// ---------------------------------------------------------------------------
// pre_poi[b,p] = vb + sum_l vw[l] * exp(-D[poi[b,l],p]/(gmax-gmin))
//                                 * (poi_emb[p] . out[b,l,:])
// ---------------------------------------------------------------------------
__global__ __launch_bounds__(256) void prepoi_kernel(
    const float* __restrict__ outp, const float* __restrict__ poi_emb,
    const int* __restrict__ poi_idx, const float* __restrict__ Dm,
    const unsigned* __restrict__ mm, const float* __restrict__ vw,
    const float* __restrict__ vbp, float* __restrict__ dstp)
{
    int b = blockIdx.y;
    int pbase = blockIdx.x << 7;
    __shared__ float sO[LL][132];
    __shared__ float sPc[128][68];
    __shared__ float sS[LL][132];
    __shared__ float svw[LL];
    __shared__ int srow[LL];
    __shared__ float red[128];
    int t = threadIdx.x;

    for (int i = t; i < 800; i += 256) {
        int l = i >> 5, c = (i & 31) << 2;
        *(float4*)&sO[l][c] = *(const float4*)(outp + (b * LL + l) * DD + c);
    }
    if (t < LL) { svw[t] = vw[t]; srow[t] = poi_idx[b * LL + t]; }
    __syncthreads();

    int nh = t & 31, mg = t >> 5;
    float acc[4][4] = {};
    for (int kb = 0; kb < 128; kb += 64) {
        for (int i = t; i < 128 * 16; i += 256) {
            int p = i >> 4, c = (i & 15) << 2;
            float4 val = {0.f, 0.f, 0.f, 0.f};
            if (pbase + p < POI_N) val = *(const float4*)(poi_emb + (pbase + p) * DD + kb + c);
            *(float4*)&sPc[p][c] = val;
        }
        __syncthreads();
#pragma unroll 4
        for (int kk = 0; kk < 64; kk += 4) {
            float4 a0 = *(const float4*)&sO[mg][kb + kk];
            float4 a1 = *(const float4*)&sO[mg + 8][kb + kk];
            float4 a2 = *(const float4*)&sO[mg + 16][kb + kk];
            float4 a3 = {0.f, 0.f, 0.f, 0.f};
            if (mg == 0) a3 = *(const float4*)&sO[24][kb + kk];
#pragma unroll
            for (int j = 0; j < 4; j++) {
                float4 p4 = *(const float4*)&sPc[nh + 32 * j][kk];
                acc[j][0] += p4.x * a0.x + p4.y * a0.y + p4.z * a0.z + p4.w * a0.w;
                acc[j][1] += p4.x * a1.x + p4.y * a1.y + p4.z * a1.z + p4.w * a1.w;
                acc[j][2] += p4.x * a2.x + p4.y * a2.y + p4.z * a2.z + p4.w * a2.w;
                acc[j][3] += p4.x * a3.x + p4.y * a3.y + p4.z * a3.z + p4.w * a3.w;
            }
        }
        __syncthreads();
    }
#pragma unroll
    for (int j = 0; j < 4; j++) {
        int pl = nh + 32 * j;
        sS[mg][pl]      = acc[j][0];
        sS[mg + 8][pl]  = acc[j][1];
        sS[mg + 16][pl] = acc[j][2];
        if (mg == 0) sS[24][pl] = acc[j][3];
    }
    __syncthreads();

    float gmax = __uint_as_float(mm[0]);
    float gmin = __uint_as_float(~mm[1]);
    float ninv = -1.0f / (gmax - gmin);
    int pp = t & 127, half = t >> 7;
    int p = pbase + pp;
    float s = 0.f;
    if (p < POI_N) {
        int l0 = half ? 13 : 0, l1 = half ? 25 : 13;
        for (int l = l0; l < l1; l++) {
            float dv = Dm[(size_t)srow[l] * POI_N + p];
            s += svw[l] * expf(dv * ninv) * sS[l][pp];
        }
    }
    if (half) red[pp] = s;
    __syncthreads();
    if (!half && p < POI_N)
        dstp[(size_t)b * POI_N + p] = s + red[pp] + vbp[0];
}

// ---------------------------------------------------------------------------
extern "C" void kernel_launch(void* const* d_in, const int* in_sizes, int n_in,
                              void* d_out, int out_size, void* d_ws, size_t ws_size,
                              hipStream_t stream)
{
    const int*   user = (const int*)d_in[0];
    const int*   poi  = (const int*)d_in[1];
    const int*   cat  = (const int*)d_in[2];
    const int*   tod  = (const int*)d_in[5];
    const int*   dow  = (const int*)d_in[6];
    const float* ue   = (const float*)d_in[8];
    const float* pe   = (const float*)d_in[9];
    const float* ce   = (const float*)d_in[10];
    const float* te   = (const float*)d_in[11];
    const float* de   = (const float*)d_in[12];
    const float* uec  = (const float*)d_in[13];
    const float* tec  = (const float*)d_in[14];
    const float* dec  = (const float*)d_in[15];
    const float* W    = (const float*)d_in[16];
    const float* Bv   = (const float*)d_in[17];
    const float* vw   = (const float*)d_in[18];
    const float* vb   = (const float*)d_in[19];
    const float* Dm   = (const float*)d_in[20];

    float* ws = (float*)d_ws;
    float* O0 = ws;
    float* C0 = ws + 204800;
    float* O1 = ws + 409600;
    float* C1 = ws + 614400;
    float* Q  = ws + 819200;
    float* Kb = ws + 1024000;
    float* V  = ws + 1228800;
    float* MV = ws + 1433600;                      // 1600 floats
    unsigned* BAR = (unsigned*)(ws + 1435200);     // 32 barrier counters
    unsigned* MM  = BAR + 32;                      // 2 minmax slots

    float* out_poi = (float*)d_out;
    float* out_cat = out_poi + BB * POI_N;

    // zero barrier counters + minmax slots (max-trick needs 0-init for both)
    hipMemsetAsync(BAR, 0, 34 * sizeof(unsigned), stream);

    minmax_kernel<<<BL, 256, 0, stream>>>(poi, Dm, MM);

    persist_kernel<<<NBLK, 256, 0, stream>>>(
        user, poi, cat, tod, dow, ue, pe, ce, te, de, uec, tec, dec,
        W, Bv, vw, vb, O0, C0, O1, C1, Q, Kb, V, MV, BAR, out_cat);

    prepoi_kernel<<<dim3(79, BB), 256, 0, stream>>>(O0, pe, poi, Dm, MM, vw, vb, out_poi);
}

// Round 3
// 1180.134 us; speedup vs baseline: 1.1539x; 1.0706x over previous
//
#include <hip/hip_runtime.h>

// Sizes
#define BB 64
#define LL 25
#define DD 128
#define BL 1600           // B*L
#define POI_N 10000
#define CAT_N 400
#define NBLK 150          // persistent-kernel grid: <= 256 CUs at 1 block/CU -> always co-resident
#define NGRP 8            // arrival shards (~= XCDs); 150 RMWs/line -> ~19/line

// ---------------------------------------------------------------------------
// Grid-wide barrier, sharded arrival.
//   R1 lesson: ACQUIRE poll emits buffer_inv PER POLL -> L2-invalidate storm.
//   R2 lesson: single-line arrival = 150 serialized cross-XCD RMWs ~= 15us.
// Now: release fetch_add to bar[id][bx&7] (8 lines, ~19 serialized adds each,
// in parallel), relaxed-poll the 8 counters until sum==NBLK, then ONE
// acquire-only fence (buffer_inv; release side already did the wbl2).
// Counters padded to 128B lines. Monotonic, memset-zeroed, no reuse.
// ---------------------------------------------------------------------------
__device__ __forceinline__ void gridbar(unsigned* __restrict__ bar, int id)
{
    __syncthreads();
    if (threadIdx.x == 0) {
        unsigned* base = bar + id * (NGRP * 32);
        __hip_atomic_fetch_add(base + (blockIdx.x & (NGRP - 1)) * 32, 1u,
                               __ATOMIC_RELEASE, __HIP_MEMORY_SCOPE_AGENT);
        for (;;) {
            unsigned s = 0;
#pragma unroll
            for (int g = 0; g < NGRP; g++)
                s += __hip_atomic_load(base + g * 32, __ATOMIC_RELAXED,
                                       __HIP_MEMORY_SCOPE_AGENT);
            if (s >= NBLK) break;
            __builtin_amdgcn_s_sleep(1);
        }
        __builtin_amdgcn_fence(__ATOMIC_ACQUIRE, "agent");   // single L1/L2 inv
    }
    __syncthreads();
}

// ---------------------------------------------------------------------------
// Distance min/max over the 1600 gathered rows (standalone: consumed only by
// prepoi; 6400 waves of memory parallelism). mm zeroed by memset; min via
// ~bits trick (all values >= 0).
// ---------------------------------------------------------------------------
__global__ __launch_bounds__(256) void minmax_kernel(
    const int* __restrict__ poi, const float* __restrict__ Dm, unsigned* __restrict__ mm)
{
    int bl = blockIdx.x;
    const float4* r = (const float4*)(Dm + (size_t)poi[bl] * POI_N);
    float mx = -1e30f, mn = 1e30f;
    for (int i = threadIdx.x; i < POI_N / 4; i += 256) {
        float4 v4 = r[i];
        mx = fmaxf(mx, fmaxf(fmaxf(v4.x, v4.y), fmaxf(v4.z, v4.w)));
        mn = fminf(mn, fminf(fminf(v4.x, v4.y), fminf(v4.z, v4.w)));
    }
    for (int off = 32; off > 0; off >>= 1) {
        mx = fmaxf(mx, __shfl_down(mx, off));
        mn = fminf(mn, __shfl_down(mn, off));
    }
    __shared__ float smx[4], smn[4];
    int lid = threadIdx.x & 63, wid = threadIdx.x >> 6;
    if (lid == 0) { smx[wid] = mx; smn[wid] = mn; }
    __syncthreads();
    if (threadIdx.x == 0) {
        mx = fmaxf(fmaxf(smx[0], smx[1]), fmaxf(smx[2], smx[3]));
        mn = fminf(fminf(smn[0], smn[1]), fminf(smn[2], smn[3]));
        atomicMax(&mm[0], __float_as_uint(mx));
        atomicMax(&mm[1], ~__float_as_uint(mn));   // min(x) = ~max(~bits)
    }
}

// ---------------------------------------------------------------------------
// Persistent ac-chain kernel: embed | 8 x (proj | corr | top3+agg) | precat.
// 25 grid barriers. Phase bodies verbatim from the verified kernels.
// ---------------------------------------------------------------------------
__global__ __launch_bounds__(256) void persist_kernel(
    const int* __restrict__ user, const int* __restrict__ poi, const int* __restrict__ cat,
    const int* __restrict__ tod, const int* __restrict__ dow,
    const float* __restrict__ ue, const float* __restrict__ pe, const float* __restrict__ ce,
    const float* __restrict__ te, const float* __restrict__ de,
    const float* __restrict__ uec, const float* __restrict__ tec, const float* __restrict__ dec,
    const float* __restrict__ W, const float* __restrict__ Bv,
    const float* __restrict__ vw, const float* __restrict__ vbp,
    float* __restrict__ O0, float* __restrict__ C0, float* __restrict__ O1, float* __restrict__ C1,
    float* __restrict__ Qb, float* __restrict__ Kb, float* __restrict__ Vb,
    float* __restrict__ MV,
    unsigned* __restrict__ bar,
    float* __restrict__ out_cat)
{
    // ---- shared memory: big region reused per phase + small persistent tail
    __shared__ __align__(16) char smem_raw[51712];     // proj/agg: sS[32][132] + sWc[128][68]
    float (*sS)[132] = reinterpret_cast<float(*)[132]>(smem_raw);
    float (*sWc)[68] = reinterpret_cast<float(*)[68]>(smem_raw + 16896);
    float* csq       = reinterpret_cast<float*>(smem_raw);              // corr: q rows [3200]
    float* csk       = reinterpret_cast<float*>(smem_raw + 12800);      // corr: k rows [3200]
    float (*crb)[4]  = reinterpret_cast<float(*)[4]>(smem_raw + 25600); // corr: rbuf[25][4]

    __shared__ float sbm[LL];          // batch-mean of mv
    __shared__ int   sidx[3];          // top-3 shifts
    __shared__ float stc[BB][3];       // per-b softmax weights
    __shared__ float yv[DD];           // precat
    __shared__ float svw[LL];          // precat

    int bx = blockIdx.x, t = threadIdx.x;

    // ================= phase E: embed gather ===============================
    for (int i = bx * 256 + t; i < 51200; i += NBLK * 256) {   // 204800 floats as float4
        int bl = i >> 5, c = (i & 31) << 2;
        int u = user[bl], p = poi[bl], cc = cat[bl], td = tod[bl], dw = dow[bl];
        float4 a0 = *(const float4*)(ue + u * DD + c);
        float4 a1 = *(const float4*)(pe + p * DD + c);
        float4 a2 = *(const float4*)(te + td * DD + c);
        float4 a3 = *(const float4*)(de + dw * DD + c);
        float4 x;
        x.x = a0.x + a1.x + a2.x + a3.x; x.y = a0.y + a1.y + a2.y + a3.y;
        x.z = a0.z + a1.z + a2.z + a3.z; x.w = a0.w + a1.w + a2.w + a3.w;
        *(float4*)(O0 + bl * DD + c) = x;
        float4 b0 = *(const float4*)(uec + u * DD + c);
        float4 b1 = *(const float4*)(ce + cc * DD + c);
        float4 b2 = *(const float4*)(tec + td * DD + c);
        float4 b3 = *(const float4*)(dec + dw * DD + c);
        float4 xc;
        xc.x = b0.x + b1.x + b2.x + b3.x; xc.y = b0.y + b1.y + b2.y + b3.y;
        xc.z = b0.z + b1.z + b2.z + b3.z; xc.w = b0.w + b1.w + b2.w + b3.w;
        *(float4*)(C0 + bl * DD + c) = xc;
    }
    gridbar(bar, 0);

    // ================= 8 autocorrelation-attention calls ===================
    float* bufs[4] = {O0, C0, O1, C1};
    const int qsel[8] = {0, 1, 2, 3, 0, 1, 2, 3};
    const int ksel[8] = {0, 1, 3, 0, 0, 1, 3, 0};
    const int dsel[8] = {2, 3, 0, 1, 2, 3, 0, 1};
    int bid = 1;

#pragma unroll 1
    for (int ci = 0; ci < 8; ++ci) {
        const float* qx  = bufs[qsel[ci]];
        const float* kx  = bufs[ksel[ci]];   // kx == vx in all calls
        float*       dst = bufs[dsel[ci]];
        const float* Wb  = W  + (size_t)ci * 4 * DD * DD;
        const float* Bb  = Bv + (size_t)ci * 4 * DD;

        // ---- proj: dst3 = src @ Wr^T + br for r in {q,k,v}; all 150 blocks
        {
            int r = bx / 50, tile = bx % 50;
            const float* src  = (r == 0) ? qx : kx;
            const float* Wm   = Wb + r * DD * DD;
            const float* bias = Bb + r * DD;
            float* pdst       = (r == 0) ? Qb : (r == 1 ? Kb : Vb);
            int mbase = tile * 32;

            for (int i = t; i < 32 * 32; i += 256) {
                int m = i >> 5, c = (i & 31) << 2;
                *(float4*)&sS[m][c] = *(const float4*)(src + (mbase + m) * DD + c);
            }
            __syncthreads();
            int nh = t & 31, mg = t >> 5;
            float acc[4][4] = {};
            for (int kb = 0; kb < 128; kb += 64) {
                for (int i = t; i < 128 * 16; i += 256) {
                    int n = i >> 4, c = (i & 15) << 2;
                    *(float4*)&sWc[n][c] = *(const float4*)(Wm + n * DD + kb + c);
                }
                __syncthreads();
#pragma unroll 4
                for (int kk = 0; kk < 64; kk += 4) {
                    float4 a[4], w[4];
#pragma unroll
                    for (int i2 = 0; i2 < 4; i2++) a[i2] = *(const float4*)&sS[mg * 4 + i2][kb + kk];
#pragma unroll
                    for (int j = 0; j < 4; j++) w[j] = *(const float4*)&sWc[nh + 32 * j][kk];
#pragma unroll
                    for (int i2 = 0; i2 < 4; i2++)
#pragma unroll
                        for (int j = 0; j < 4; j++)
                            acc[i2][j] += a[i2].x * w[j].x + a[i2].y * w[j].y +
                                          a[i2].z * w[j].z + a[i2].w * w[j].w;
                }
                __syncthreads();
            }
#pragma unroll
            for (int i2 = 0; i2 < 4; i2++) {
                int m = mbase + mg * 4 + i2;
#pragma unroll
                for (int j = 0; j < 4; j++) {
                    int n = nh + 32 * j;
                    pdst[m * DD + n] = acc[i2][j] + bias[n];
                }
            }
        }
        gridbar(bar, bid++);

        // ---- corr: mv[b,tau] = (1/128) sum_s q[b,(s+tau)%25,:].k[b,s,:]; 64 blocks
        if (bx < BB) {
            int b = bx;
            for (int i = t; i < 800; i += 256) {
                int c = i << 2;
                *(float4*)&csq[c] = *(const float4*)(Qb + b * LL * DD + c);
                *(float4*)&csk[c] = *(const float4*)(Kb + b * LL * DD + c);
            }
            __syncthreads();
            int lid = t & 63, wid = t >> 6;
            for (int tau = 0; tau < LL; tau++) {
                float s = 0.f;
                for (int e = t; e < 800; e += 256) {        // float4 granularity
                    int srow = e >> 5, dc = (e & 31) << 2;
                    int qrow = srow + tau; if (qrow >= LL) qrow -= LL;
                    float4 a = *(const float4*)&csq[qrow * DD + dc];
                    float4 g = *(const float4*)&csk[srow * DD + dc];
                    s += a.x * g.x + a.y * g.y + a.z * g.z + a.w * g.w;
                }
                for (int off = 32; off > 0; off >>= 1) s += __shfl_down(s, off);
                if (lid == 0) crb[tau][wid] = s;
            }
            __syncthreads();
            if (t < LL)
                MV[b * LL + t] = (crb[t][0] + crb[t][1] + crb[t][2] + crb[t][3]) * (1.0f / 128.0f);
        }
        gridbar(bar, bid++);

        // ---- top3 (redundant per block) + softmax + agg + out-proj; 50 blocks
        if (bx < 50) {
            int mbase = bx * 32;
            if (t < LL) {
                float s = 0.f;
                for (int b2 = 0; b2 < BB; b2++) s += MV[b2 * LL + t];
                sbm[t] = s;
            }
            __syncthreads();
            if (t == 0) {
                float loc[LL];
                for (int i = 0; i < LL; i++) loc[i] = sbm[i];
                for (int j = 0; j < 3; j++) {
                    int bi = 0; float bvv = loc[0];
                    for (int i = 1; i < LL; i++) if (loc[i] > bvv) { bvv = loc[i]; bi = i; }
                    sidx[j] = bi; loc[bi] = -1e30f;
                }
            }
            __syncthreads();
            if (t < BB) {
                float w0 = MV[t * LL + sidx[0]];
                float w1 = MV[t * LL + sidx[1]];
                float w2 = MV[t * LL + sidx[2]];
                float m = fmaxf(w0, fmaxf(w1, w2));
                float e0 = expf(w0 - m), e1 = expf(w1 - m), e2 = expf(w2 - m);
                float inv = 1.0f / (e0 + e1 + e2);
                stc[t][0] = e0 * inv; stc[t][1] = e1 * inv; stc[t][2] = e2 * inv;
            }
            __syncthreads();
            int i0 = sidx[0], i1 = sidx[1], i2x = sidx[2];
            const float* Wm   = Wb + 3 * DD * DD;
            const float* bias = Bb + 3 * DD;

            for (int i = t; i < 32 * 32; i += 256) {
                int m = i >> 5, c = (i & 31) << 2;
                int row = mbase + m;
                int b = row / LL, l = row - b * LL;
                int l0 = l + i0;  if (l0 >= LL) l0 -= LL;
                int l1 = l + i1;  if (l1 >= LL) l1 -= LL;
                int l2 = l + i2x; if (l2 >= LL) l2 -= LL;
                float w0 = stc[b][0], w1 = stc[b][1], w2 = stc[b][2];
                float4 v0 = *(const float4*)(Vb + (b * LL + l0) * DD + c);
                float4 v1 = *(const float4*)(Vb + (b * LL + l1) * DD + c);
                float4 v2 = *(const float4*)(Vb + (b * LL + l2) * DD + c);
                float4 a;
                a.x = w0 * v0.x + w1 * v1.x + w2 * v2.x;
                a.y = w0 * v0.y + w1 * v1.y + w2 * v2.y;
                a.z = w0 * v0.z + w1 * v1.z + w2 * v2.z;
                a.w = w0 * v0.w + w1 * v1.w + w2 * v2.w;
                *(float4*)&sS[m][c] = a;
            }
            __syncthreads();
            int nh = t & 31, mg = t >> 5;
            float acc[4][4] = {};
            for (int kb = 0; kb < 128; kb += 64) {
                for (int i = t; i < 128 * 16; i += 256) {
                    int n = i >> 4, c = (i & 15) << 2;
                    *(float4*)&sWc[n][c] = *(const float4*)(Wm + n * DD + kb + c);
                }
                __syncthreads();
#pragma unroll 4
                for (int kk = 0; kk < 64; kk += 4) {
                    float4 a[4], w[4];
#pragma unroll
                    for (int ii = 0; ii < 4; ii++) a[ii] = *(const float4*)&sS[mg * 4 + ii][kb + kk];
#pragma unroll
                    for (int j = 0; j < 4; j++) w[j] = *(const float4*)&sWc[nh + 32 * j][kk];
#pragma unroll
                    for (int ii = 0; ii < 4; ii++)
#pragma unroll
                        for (int j = 0; j < 4; j++)
                            acc[ii][j] += a[ii].x * w[j].x + a[ii].y * w[j].y +
                                          a[ii].z * w[j].z + a[ii].w * w[j].w;
                }
                __syncthreads();
            }
#pragma unroll
            for (int ii = 0; ii < 4; ii++) {
                int m = mbase + mg * 4 + ii;
#pragma unroll
                for (int j = 0; j < 4; j++) {
                    int n = nh + 32 * j;
                    dst[m * DD + n] = acc[ii][j] + bias[n];
                }
            }
        }
        gridbar(bar, bid++);
    }

    // ================= precat tail (64 blocks) =============================
    if (bx < BB) {
        int b = bx;
        if (t < LL) svw[t] = vw[t];
        __syncthreads();
        if (t < DD) {
            float s = 0.f;
            for (int l = 0; l < LL; l++) s += svw[l] * C0[(b * LL + l) * DD + t];
            yv[t] = s;
        }
        __syncthreads();
        float vb = vbp[0];
        for (int c = t; c < CAT_N; c += 256) {
            float s = 0.f;
            for (int d = 0; d < DD; d += 4) {
                float4 ce4 = *(const float4*)(ce + c * DD + d);
                s += ce4.x * yv[d] + ce4.y * yv[d + 1] + ce4.z * yv[d + 2] + ce4.w * yv[d + 3];
            }
            out_cat[b * CAT_N + c] = s + vb;
        }
    }
}

// ---------------------------------------------------------------------------
// pre_poi[b,p] = vb + sum_l vw[l] * exp(-D[poi[b,l],p]/(gmax-gmin))
//                                 * (poi_emb[p] . out[b,l,:])
// ---------------------------------------------------------------------------
__global__ __launch_bounds__(256) void prepoi_kernel(
    const float* __restrict__ outp, const float* __restrict__ poi_emb,
    const int* __restrict__ poi_idx, const float* __restrict__ Dm,
    const unsigned* __restrict__ mm, const float* __restrict__ vw,
    const float* __restrict__ vbp, float* __restrict__ dstp)
{
    int b = blockIdx.y;
    int pbase = blockIdx.x << 7;
    __shared__ float sO[LL][132];
    __shared__ float sPc[128][68];
    __shared__ float sS[LL][132];
    __shared__ float svw[LL];
    __shared__ int srow[LL];
    __shared__ float red[128];
    int t = threadIdx.x;

    for (int i = t; i < 800; i += 256) {
        int l = i >> 5, c = (i & 31) << 2;
        *(float4*)&sO[l][c] = *(const float4*)(outp + (b * LL + l) * DD + c);
    }
    if (t < LL) { svw[t] = vw[t]; srow[t] = poi_idx[b * LL + t]; }
    __syncthreads();

    int nh = t & 31, mg = t >> 5;
    float acc[4][4] = {};
    for (int kb = 0; kb < 128; kb += 64) {
        for (int i = t; i < 128 * 16; i += 256) {
            int p = i >> 4, c = (i & 15) << 2;
            float4 val = {0.f, 0.f, 0.f, 0.f};
            if (pbase + p < POI_N) val = *(const float4*)(poi_emb + (pbase + p) * DD + kb + c);
            *(float4*)&sPc[p][c] = val;
        }
        __syncthreads();
#pragma unroll 4
        for (int kk = 0; kk < 64; kk += 4) {
            float4 a0 = *(const float4*)&sO[mg][kb + kk];
            float4 a1 = *(const float4*)&sO[mg + 8][kb + kk];
            float4 a2 = *(const float4*)&sO[mg + 16][kb + kk];
            float4 a3 = {0.f, 0.f, 0.f, 0.f};
            if (mg == 0) a3 = *(const float4*)&sO[24][kb + kk];
#pragma unroll
            for (int j = 0; j < 4; j++) {
                float4 p4 = *(const float4*)&sPc[nh + 32 * j][kk];
                acc[j][0] += p4.x * a0.x + p4.y * a0.y + p4.z * a0.z + p4.w * a0.w;
                acc[j][1] += p4.x * a1.x + p4.y * a1.y + p4.z * a1.z + p4.w * a1.w;
                acc[j][2] += p4.x * a2.x + p4.y * a2.y + p4.z * a2.z + p4.w * a2.w;
                acc[j][3] += p4.x * a3.x + p4.y * a3.y + p4.z * a3.z + p4.w * a3.w;
            }
        }
        __syncthreads();
    }
#pragma unroll
    for (int j = 0; j < 4; j++) {
        int pl = nh + 32 * j;
        sS[mg][pl]      = acc[j][0];
        sS[mg + 8][pl]  = acc[j][1];
        sS[mg + 16][pl] = acc[j][2];
        if (mg == 0) sS[24][pl] = acc[j][3];
    }
    __syncthreads();

    float gmax = __uint_as_float(mm[0]);
    float gmin = __uint_as_float(~mm[1]);
    float ninv = -1.0f / (gmax - gmin);
    int pp = t & 127, half = t >> 7;
    int p = pbase + pp;
    float s = 0.f;
    if (p < POI_N) {
        int l0 = half ? 13 : 0, l1 = half ? 25 : 13;
        for (int l = l0; l < l1; l++) {
            float dv = Dm[(size_t)srow[l] * POI_N + p];
            s += svw[l] * expf(dv * ninv) * sS[l][pp];
        }
    }
    if (half) red[pp] = s;
    __syncthreads();
    if (!half && p < POI_N)
        dstp[(size_t)b * POI_N + p] = s + red[pp] + vbp[0];
}

// ---------------------------------------------------------------------------
extern "C" void kernel_launch(void* const* d_in, const int* in_sizes, int n_in,
                              void* d_out, int out_size, void* d_ws, size_t ws_size,
                              hipStream_t stream)
{
    const int*   user = (const int*)d_in[0];
    const int*   poi  = (const int*)d_in[1];
    const int*   cat  = (const int*)d_in[2];
    const int*   tod  = (const int*)d_in[5];
    const int*   dow  = (const int*)d_in[6];
    const float* ue   = (const float*)d_in[8];
    const float* pe   = (const float*)d_in[9];
    const float* ce   = (const float*)d_in[10];
    const float* te   = (const float*)d_in[11];
    const float* de   = (const float*)d_in[12];
    const float* uec  = (const float*)d_in[13];
    const float* tec  = (const float*)d_in[14];
    const float* dec  = (const float*)d_in[15];
    const float* W    = (const float*)d_in[16];
    const float* Bv   = (const float*)d_in[17];
    const float* vw   = (const float*)d_in[18];
    const float* vb   = (const float*)d_in[19];
    const float* Dm   = (const float*)d_in[20];

    float* ws = (float*)d_ws;
    float* O0 = ws;
    float* C0 = ws + 204800;
    float* O1 = ws + 409600;
    float* C1 = ws + 614400;
    float* Q  = ws + 819200;
    float* Kb = ws + 1024000;
    float* V  = ws + 1228800;
    float* MV = ws + 1433600;                      // 1600 floats
    unsigned* BAR = (unsigned*)(ws + 1435200);     // 25 barriers x 8 groups x 32 uints
    unsigned* MM  = BAR + 25 * NGRP * 32;          // 2 minmax slots

    float* out_poi = (float*)d_out;
    float* out_cat = out_poi + BB * POI_N;

    // zero barrier counters + minmax slots (max-trick needs 0-init for both)
    hipMemsetAsync(BAR, 0, (25 * NGRP * 32 + 2) * sizeof(unsigned), stream);

    minmax_kernel<<<BL, 256, 0, stream>>>(poi, Dm, MM);

    persist_kernel<<<NBLK, 256, 0, stream>>>(
        user, poi, cat, tod, dow, ue, pe, ce, te, de, uec, tec, dec,
        W, Bv, vw, vb, O0, C0, O1, C1, Q, Kb, V, MV, BAR, out_cat);

    prepoi_kernel<<<dim3(79, BB), 256, 0, stream>>>(O0, pe, poi, Dm, MM, vw, vb, out_poi);
}